// Round 10
// baseline (564.825 us; speedup 1.0000x reference)
//
#include <hip/hip_runtime.h>
#include <hip/hip_bf16.h>

#define N_EMBD 1024
#define NW     110592
#define NCHUNK 96

typedef __attribute__((ext_vector_type(8)))  short          short8;
typedef __attribute__((ext_vector_type(8)))  unsigned short ushort8;
typedef __attribute__((ext_vector_type(16))) float          floatx16;
typedef __attribute__((ext_vector_type(4)))  float          float4v;

// chunk sizes: 48 x 1024, 24 x 2048, 24 x 512
__device__ __forceinline__ void chunk_info(int l, int& S, int& off) {
  if (l < 48)      { S = 1024; off = l * 1024; }
  else if (l < 72) { S = 2048; off = 49152 + (l - 48) * 2048; }
  else             { S = 512;  off = 98304 + (l - 72) * 512; }
}

__device__ __forceinline__ unsigned short f2bf(float f) {
  unsigned u = __float_as_uint(f);
  u += 0x7fffu + ((u >> 16) & 1u);
  return (unsigned short)(u >> 16);
}
__device__ __forceinline__ float bf2f(unsigned short u) {
  return __uint_as_float(((unsigned)u) << 16);
}

#define GLOAD_LDS16(g, l) \
  __builtin_amdgcn_global_load_lds((const __attribute__((address_space(1))) unsigned int*)(g), \
                                   (__attribute__((address_space(3))) unsigned int*)(l), 16, 0, 0)

// ---- chunk-dependency flags (device globals, zero-init at load; every launch
// returns them to zero -> deterministic across graph replays)
__device__ unsigned g_xp[NCHUNK];   // xpose quarters done (target 4)
__device__ unsigned g_en[NCHUNK];   // enc tiles done (target 4; 4th does LN)
__device__ unsigned g_ln[NCHUNK];   // LN done (target 1)
__device__ unsigned g_dc[NCHUNK];   // dec tiles done (target S/256; last resets)

__device__ __forceinline__ unsigned agent_add(unsigned* p) {
  return __hip_atomic_fetch_add(p, 1u, __ATOMIC_ACQ_REL, __HIP_MEMORY_SCOPE_AGENT);
}
__device__ __forceinline__ void agent_store(unsigned* p, unsigned v) {
  __hip_atomic_store(p, v, __ATOMIC_RELEASE, __HIP_MEMORY_SCOPE_AGENT);
}
__device__ __forceinline__ void spin_ge(unsigned* p, unsigned tgt) {
  while (__hip_atomic_load(p, __ATOMIC_ACQUIRE, __HIP_MEMORY_SCOPE_AGENT) < tgt)
    __builtin_amdgcn_s_sleep(2);
}

// ---- R6's counted-vmcnt GEMM K-loop (verbatim structure). Assumes vmcnt==0 on
// entry. 32(batch) x 256(col) tile, K-step 32, 2-buf LDS, vmcnt(6) steady.
#define STAGE4(buf, k0, Wg, WROW) { _Pragma("unroll")                            \
    for (int q = 0; q < 4; ++q)                                                  \
      GLOAD_LDS16((Wg) + (size_t)((k0) + w * 4 + q) * (WROW), &Bt[buf][w * 4 + q][0]); }
#define AFL(Ab, k0, ks) (*(const short8*)((Ab) + (size_t)((k0) + (ks) * 16 + hi * 8) * 32))

#define KLOOP(Ab, Wg, WROW, NT, ACC) {                                           \
    short8 aA0 = AFL(Ab, 0, 0), aA1 = AFL(Ab, 0, 1);                             \
    STAGE4(0, 0, Wg, WROW);                                                      \
    asm volatile("" ::: "memory");                                               \
    for (int t = 0; t < (NT); ++t) {                                             \
      int k0 = t << 5, cur = t & 1;                                              \
      short8 aB0, aB1;                                                           \
      if (t + 1 < (NT)) {                                                        \
        aB0 = AFL(Ab, k0 + 32, 0); aB1 = AFL(Ab, k0 + 32, 1);                    \
        STAGE4(cur ^ 1, k0 + 32, Wg, WROW);                                      \
        __builtin_amdgcn_sched_barrier(0);                                       \
        asm volatile("s_waitcnt vmcnt(6)" ::: "memory");                         \
      } else {                                                                   \
        __builtin_amdgcn_sched_barrier(0);                                       \
        asm volatile("s_waitcnt vmcnt(0)" ::: "memory");                         \
      }                                                                          \
      __builtin_amdgcn_s_barrier();                                              \
      __builtin_amdgcn_sched_barrier(0);                                         \
      short8 bf0, bf1;                                                           \
      _Pragma("unroll")                                                          \
      for (int jj = 0; jj < 8; ++jj) bf0[jj] = (short)f2bf(Bt[cur][hi * 8 + jj][w * 32 + lo]); \
      _Pragma("unroll")                                                          \
      for (int jj = 0; jj < 8; ++jj) bf1[jj] = (short)f2bf(Bt[cur][16 + hi * 8 + jj][w * 32 + lo]); \
      ACC = __builtin_amdgcn_mfma_f32_32x32x16_bf16(aA0, bf0, ACC, 0, 0, 0);     \
      ACC = __builtin_amdgcn_mfma_f32_32x32x16_bf16(aA1, bf1, ACC, 0, 0, 0);     \
      __builtin_amdgcn_sched_barrier(0);                                         \
      __builtin_amdgcn_s_barrier();                                              \
      __builtin_amdgcn_sched_barrier(0);                                         \
      aA0 = aB0; aA1 = aB1;                                                      \
    } }

// ===== fused persistent kernel: xpose -> enc -> LN -> dec via per-chunk flags.
// 432 blocks x 512 thr, LDS 64KB -> 2 blocks/CU, 432 <= 512 slots: all resident.
__global__ __launch_bounds__(512, 4) void fused_kernel(
    const float* __restrict__ P, const float* __restrict__ We,
    const float* __restrict__ Wd, const float* __restrict__ gamma,
    const float* __restrict__ beta, unsigned short* __restrict__ xswz,
    unsigned short* __restrict__ reps, unsigned short* __restrict__ rlnswz,
    float* __restrict__ out) {
  __shared__ float Bt[2][32][256];
  __shared__ unsigned s_who;
  int id = blockIdx.x, tid = threadIdx.x;
  int w = tid >> 6, lane = tid & 63, lo = lane & 31, hi = lane >> 5;
  int x = id & 7;

  // dec mapping (all 432 blocks; per-XCD heavy-first; chunk l on XCD l&7)
  int jD = id >> 3, lD, tiD;
  if (jD < 24)      { lD = 48 + x + 8 * (jD >> 3); tiD = jD & 7; }
  else if (jD < 48) { int jm = jD - 24; lD = x + 8 * (jm >> 2); tiD = jm & 3; }
  else              { int jl = jD - 48; lD = 72 + x + 8 * (jl >> 1); tiD = jl & 1; }
  int SD, offD; chunk_info(lD, SD, offD);

  if (id < 384) {
    int jE = id >> 3, lE, tiE;
    if (jE < 12)      { lE = 48 + x + 8 * (jE >> 2); tiE = jE & 3; }
    else if (jE < 36) { int jm = jE - 12; lE = x + 8 * (jm >> 2); tiE = jm & 3; }
    else              { int jl = jE - 36; lE = 72 + x + 8 * (jl >> 2); tiE = jl & 3; }
    int SE, offE; chunk_info(lE, SE, offE);

    // ---- phase X: transpose my K-quarter of chunk lE's A-slice into xswz
    {
      int kq0 = offE + tiE * (SE >> 2);      // element offset, multiple of 8
      int iters = SE >> 9;                   // SE/512 items per thread
      for (int it = 0; it < iters; ++it) {
        int item = it * 512 + tid;           // 0..SE-1
        int kbl = item >> 5, b = item & 31;
        const float* src = P + (size_t)b * NW + kq0 + kbl * 8;
        float4v v0 = *(const float4v*)(src);
        float4v v1 = *(const float4v*)(src + 4);
        ushort8 o;
#pragma unroll
        for (int q = 0; q < 4; ++q) { o[q] = f2bf(v0[q]); o[q + 4] = f2bf(v1[q]); }
        *(ushort8*)(xswz + ((size_t)((kq0 >> 3) + kbl) * 32 + b) * 8) = o;
      }
    }
    if (tid == 0) { __threadfence(); agent_add(&g_xp[lE]); }
    if (tid == 0) { spin_ge(&g_xp[lE], 4); __threadfence(); }
    __syncthreads();

    // ---- phase E: enc GEMM tile (cols tiE*256..+255)
    asm volatile("s_waitcnt vmcnt(0)" ::: "memory");   // clear stores/atomics from count
    int c0E = tiE * 256;
    const float* WgE = We + (size_t)lE * (2048 * N_EMBD) + c0E + (lane << 2);
    const unsigned short* AbE = xswz + (size_t)offE * 32 + lo * 8;
    floatx16 acc = {};
    int ntE = SE >> 5;
    KLOOP(AbE, WgE, N_EMBD, ntE, acc);

    unsigned short* outp = reps + (size_t)(lE * 32) * N_EMBD + c0E + w * 32 + lo;
#pragma unroll
    for (int r = 0; r < 16; ++r) {
      int row = (r & 3) + 8 * (r >> 2) + 4 * hi;
      outp[(size_t)row * N_EMBD] = f2bf(acc[r]);
    }

    // ---- arrive enc; 4th arriver runs LN for the whole chunk
    if (tid == 0) { __threadfence(); s_who = agent_add(&g_en[lE]); }
    __syncthreads();
    if (s_who == 3) {
      if (tid == 0) {
        agent_store(&g_xp[lE], 0);   // all 4 siblings have passed their spin
        agent_store(&g_en[lE], 0);
        __threadfence();
      }
      // LN: wave w handles rows w*4..w*4+3 (math identical to R6 ln_kernel)
      for (int r4 = 0; r4 < 4; ++r4) {
        int b = w * 4 + r4;
        const unsigned short* rp = reps + ((size_t)lE * 32 + b) * N_EMBD;
        float xv[16];
#pragma unroll
        for (int jj = 0; jj < 2; ++jj) {
          int g = jj * 64 + lane;
          ushort8 v = *(const ushort8*)(rp + g * 8);
#pragma unroll
          for (int tt = 0; tt < 8; ++tt) xv[jj * 8 + tt] = bf2f(v[tt]);
        }
        float s = 0.f, s2 = 0.f;
#pragma unroll
        for (int i = 0; i < 16; ++i) { s += xv[i]; s2 += xv[i] * xv[i]; }
#pragma unroll
        for (int m = 1; m < 64; m <<= 1) {
          s  += __shfl_xor(s,  m, 64);
          s2 += __shfl_xor(s2, m, 64);
        }
        float mu  = s * (1.f / 1024.f);
        float var = s2 * (1.f / 1024.f) - mu * mu;
        float rs  = rsqrtf(var + 1e-5f);
        unsigned short* op = rlnswz + (size_t)lE * 32768 + b * 8;
#pragma unroll
        for (int jj = 0; jj < 2; ++jj) {
          int g = jj * 64 + lane;
          float4v g0 = *(const float4v*)(gamma + g * 8);
          float4v g1 = *(const float4v*)(gamma + g * 8 + 4);
          float4v b0 = *(const float4v*)(beta + g * 8);
          float4v b1 = *(const float4v*)(beta + g * 8 + 4);
          ushort8 o;
#pragma unroll
          for (int tt = 0; tt < 4; ++tt) {
            o[tt]     = f2bf((xv[jj * 8 + tt]     - mu) * rs * g0[tt] + b0[tt]);
            o[tt + 4] = f2bf((xv[jj * 8 + 4 + tt] - mu) * rs * g1[tt] + b1[tt]);
          }
          *(ushort8*)(op + (size_t)g * 256) = o;
        }
      }
      if (tid == 0) { __threadfence(); agent_store(&g_ln[lE], 1); }
    }
  }

  // ---- phase D: dec GEMM tile (chunk lD, cols tiD*256..+255)
  if (tid == 0) { spin_ge(&g_ln[lD], 1); __threadfence(); }
  __syncthreads();
  asm volatile("s_waitcnt vmcnt(0)" ::: "memory");
  int c0D = tiD * 256;
  const float* WgD = Wd + (size_t)lD * (N_EMBD * 2048) + c0D + (lane << 2);
  const unsigned short* AbD = rlnswz + (size_t)lD * 32768 + lo * 8;
  floatx16 accD = {};
  KLOOP(AbD, WgD, 2048, 32, accD);

#pragma unroll
  for (int r = 0; r < 16; ++r) {
    int row = (r & 3) + 8 * (r >> 2) + 4 * hi;
    out[(size_t)row * NW + offD + c0D + w * 32 + lo] = accD[r];
  }

  // ---- last dec consumer of chunk lD resets its flags for the next replay
  if (tid == 0) {
    unsigned n = agent_add(&g_dc[lD]);
    if (n == (unsigned)(SD >> 8) - 1) {
      agent_store(&g_ln[lD], 0);
      agent_store(&g_dc[lD], 0);
    }
  }
}

extern "C" void kernel_launch(void* const* d_in, const int* in_sizes, int n_in,
                              void* d_out, int out_size, void* d_ws, size_t ws_size,
                              hipStream_t stream) {
  const float* P  = (const float*)d_in[0];
  const float* We = (const float*)d_in[1];
  const float* Wd = (const float*)d_in[2];
  const float* g  = (const float*)d_in[3];
  const float* bt = (const float*)d_in[4];
  float* out = (float*)d_out;

  unsigned short* xswz   = (unsigned short*)d_ws;                    // NW*32 bf16 = 7.08 MB
  unsigned short* reps   = xswz + (size_t)NW * 32;                   // 6.29 MB
  unsigned short* rlnswz = reps + (size_t)NCHUNK * 32 * N_EMBD;      // 6.29 MB

  fused_kernel<<<432, 512, 0, stream>>>(P, We, Wd, g, bt, xswz, reps, rlnswz, out);
}

// Round 11
// 203.580 us; speedup vs baseline: 2.7745x; 2.7745x over previous
//
#include <hip/hip_runtime.h>
#include <hip/hip_bf16.h>

#define N_EMBD 1024
#define NW     110592
#define NCHUNK 96

typedef __attribute__((ext_vector_type(8)))  short          short8;
typedef __attribute__((ext_vector_type(8)))  unsigned short ushort8;
typedef __attribute__((ext_vector_type(16))) float          floatx16;
typedef __attribute__((ext_vector_type(4)))  float          float4v;

// chunk sizes: 48 x 1024, 24 x 2048, 24 x 512
__device__ __forceinline__ void chunk_info(int l, int& S, int& off) {
  if (l < 48)      { S = 1024; off = l * 1024; }
  else if (l < 72) { S = 2048; off = 49152 + (l - 48) * 2048; }
  else             { S = 512;  off = 98304 + (l - 72) * 512; }
}

// fp32 -> bf16 round-to-nearest-even
__device__ __forceinline__ unsigned short f2bf(float f) {
  unsigned u = __float_as_uint(f);
  u += 0x7fffu + ((u >> 16) & 1u);
  return (unsigned short)(u >> 16);
}
__device__ __forceinline__ float bf2f(unsigned short u) {
  return __uint_as_float(((unsigned)u) << 16);
}

#define GLOAD_LDS16(g, l) \
  __builtin_amdgcn_global_load_lds((const __attribute__((address_space(1))) unsigned int*)(g), \
                                   (__attribute__((address_space(3))) unsigned int*)(l), 16, 0, 0)

// ---------------- transpose: xswz[kb][b][e] = bf16(P[b][kb*8+e])
__global__ __launch_bounds__(256) void xpose_kernel(
    const float* __restrict__ P, unsigned short* __restrict__ xswz) {
  int t = blockIdx.x * 256 + threadIdx.x;   // t < (NW/8)*32
  int b = t & 31, kb = t >> 5;
  const float* src = P + (size_t)b * NW + (size_t)kb * 8;
  float4v v0 = *(const float4v*)(src);
  float4v v1 = *(const float4v*)(src + 4);
  ushort8 o;
#pragma unroll
  for (int j = 0; j < 4; ++j) { o[j] = f2bf(v0[j]); o[j + 4] = f2bf(v1[j]); }
  *(ushort8*)(xswz + (size_t)t * 8) = o;
}

// ---------------- encoder: reps[l*32+b][d] = sum_k x[b,off+k] * We[l][k][d]
// 384 blocks x 512 thr (8 waves). 32(batch) x 256(col) tile, K-step 32, LDS dbuf.
// T4 counted-vmcnt K-loop: prefetch loads (2 A + 4 stage) stay in flight across
// raw barriers; vmcnt(6) retires exactly the previous tile's loads. Two barriers
// per iter: b1 = RAW (stage done), b2 = WAR (reads done before next stage-write).
__global__ __launch_bounds__(512) void enc_kernel(
    const unsigned short* __restrict__ xswz, const float* __restrict__ We,
    unsigned short* __restrict__ reps) {
  __shared__ float Bt[2][32][256];
  int id = blockIdx.x;
  int x = id & 7, j = id >> 3;                 // j in 0..47 per XCD
  int l, ti;
  if (j < 12)      { l = 48 + x + 8 * (j >> 2); ti = j & 3; }                    // heavy  S=2048
  else if (j < 36) { int jm = j - 12; l = x + 8 * (jm >> 2); ti = jm & 3; }      // medium S=1024
  else             { int jl = j - 36; l = 72 + x + 8 * (jl >> 2); ti = jl & 3; } // light  S=512
  int S, off; chunk_info(l, S, off);

  int tid = threadIdx.x, w = tid >> 6, lane = tid & 63;
  int lo = lane & 31, hi = lane >> 5;
  int c0 = ti * 256;

  const float* Wb = We + (size_t)l * (2048 * N_EMBD) + c0 + (lane << 2);
  const unsigned short* Ab = xswz + (size_t)off * 32 + lo * 8;

#define STAGE(buf, k0) { _Pragma("unroll") \
    for (int q = 0; q < 4; ++q) \
      GLOAD_LDS16(Wb + (size_t)((k0) + w * 4 + q) * N_EMBD, &Bt[buf][w * 4 + q][0]); }
#define AFL(k0, ks) (*(const short8*)(Ab + (size_t)((k0) + (ks) * 16 + hi * 8) * 32))

  floatx16 acc = {};
  short8 aA0 = AFL(0, 0), aA1 = AFL(0, 1);
  STAGE(0, 0);
  asm volatile("" ::: "memory");

  int nt = S >> 5;
  for (int t = 0; t < nt; ++t) {
    int k0 = t << 5, cur = t & 1;
    short8 aB0, aB1;
    if (t + 1 < nt) {
      aB0 = AFL(k0 + 32, 0); aB1 = AFL(k0 + 32, 1);
      STAGE(cur ^ 1, k0 + 32);
      __builtin_amdgcn_sched_barrier(0);
      asm volatile("s_waitcnt vmcnt(6)" ::: "memory");
    } else {
      __builtin_amdgcn_sched_barrier(0);
      asm volatile("s_waitcnt vmcnt(0)" ::: "memory");
    }
    __builtin_amdgcn_s_barrier();
    __builtin_amdgcn_sched_barrier(0);
    short8 bf0, bf1;
#pragma unroll
    for (int jj = 0; jj < 8; ++jj) bf0[jj] = (short)f2bf(Bt[cur][hi * 8 + jj][w * 32 + lo]);
#pragma unroll
    for (int jj = 0; jj < 8; ++jj) bf1[jj] = (short)f2bf(Bt[cur][16 + hi * 8 + jj][w * 32 + lo]);
    acc = __builtin_amdgcn_mfma_f32_32x32x16_bf16(aA0, bf0, acc, 0, 0, 0);
    acc = __builtin_amdgcn_mfma_f32_32x32x16_bf16(aA1, bf1, acc, 0, 0, 0);
    __builtin_amdgcn_sched_barrier(0);
    __builtin_amdgcn_s_barrier();
    __builtin_amdgcn_sched_barrier(0);
    aA0 = aB0; aA1 = aB1;
  }
#undef STAGE
#undef AFL

  // C/D: col = lane&31, row = (reg&3)+8*(reg>>2)+4*(lane>>5)
  unsigned short* outp = reps + (size_t)(l * 32) * N_EMBD + c0 + w * 32 + lo;
#pragma unroll
  for (int r = 0; r < 16; ++r) {
    int row = (r & 3) + 8 * (r >> 2) + 4 * hi;
    outp[(size_t)row * N_EMBD] = f2bf(acc[r]);
  }
}

// ---------------- layernorm rows of reps -> rlnswz in blocked layout
// rlnswz elem addr = l*32768 + (d>>3)*256 + b*8 + (d&7). grid 768 x 256, wave/row.
__global__ __launch_bounds__(256) void ln_kernel(
    const unsigned short* __restrict__ reps, const float* __restrict__ gamma,
    const float* __restrict__ beta, unsigned short* __restrict__ rlnswz) {
  int row  = blockIdx.x * 4 + (threadIdx.x >> 6);
  int lane = threadIdx.x & 63;
  int l = row >> 5, b = row & 31;
  const unsigned short* rp = reps + (size_t)row * N_EMBD;

  float x[16];
#pragma unroll
  for (int j = 0; j < 2; ++j) {
    int g = j * 64 + lane;
    ushort8 v = *(const ushort8*)(rp + g * 8);
#pragma unroll
    for (int t = 0; t < 8; ++t) x[j * 8 + t] = bf2f(v[t]);
  }
  float s = 0.f, s2 = 0.f;
#pragma unroll
  for (int i = 0; i < 16; ++i) { s += x[i]; s2 += x[i] * x[i]; }
#pragma unroll
  for (int m = 1; m < 64; m <<= 1) {
    s  += __shfl_xor(s,  m, 64);
    s2 += __shfl_xor(s2, m, 64);
  }
  float mu  = s * (1.f / 1024.f);
  float var = s2 * (1.f / 1024.f) - mu * mu;
  float rs  = rsqrtf(var + 1e-5f);

  unsigned short* op = rlnswz + (size_t)l * 32768 + b * 8;
#pragma unroll
  for (int j = 0; j < 2; ++j) {
    int g = j * 64 + lane;
    float4v g0 = *(const float4v*)(gamma + g * 8);
    float4v g1 = *(const float4v*)(gamma + g * 8 + 4);
    float4v b0 = *(const float4v*)(beta + g * 8);
    float4v b1 = *(const float4v*)(beta + g * 8 + 4);
    ushort8 o;
#pragma unroll
    for (int t = 0; t < 4; ++t) {
      o[t]     = f2bf((x[j * 8 + t]     - mu) * rs * g0[t] + b0[t]);
      o[t + 4] = f2bf((x[j * 8 + 4 + t] - mu) * rs * g1[t] + b1[t]);
    }
    *(ushort8*)(op + (size_t)g * 256) = o;
  }
}

// ---------------- decoder: out[b][off+j] = sum_d rln[l*32+b][d] * Wd[l][d][j]
// 432 blocks x 512 thr, 32 x 256 tiles, K = 1024. Same counted-vmcnt K-loop.
__global__ __launch_bounds__(512) void dec_kernel(
    const unsigned short* __restrict__ rlnswz, const float* __restrict__ Wd,
    float* __restrict__ out) {
  __shared__ float Bt[2][32][256];
  int id = blockIdx.x;
  int x = id & 7, j = id >> 3;                 // j in 0..53 per XCD
  int l, ti;
  if (j < 24)      { l = 48 + x + 8 * (j >> 3); ti = j & 7; }                    // heavy  S=2048
  else if (j < 48) { int jm = j - 24; l = x + 8 * (jm >> 2); ti = jm & 3; }      // medium S=1024
  else             { int jl = j - 48; l = 72 + x + 8 * (jl >> 1); ti = jl & 1; } // light  S=512
  int S, off; chunk_info(l, S, off);

  int tid = threadIdx.x, w = tid >> 6, lane = tid & 63;
  int lo = lane & 31, hi = lane >> 5;
  int c0 = ti * 256;

  const float* Wb = Wd + (size_t)l * (N_EMBD * 2048) + c0 + (lane << 2);
  const unsigned short* Ab = rlnswz + (size_t)l * 32768 + lo * 8;

#define STAGE(buf, k0) { _Pragma("unroll") \
    for (int q = 0; q < 4; ++q) \
      GLOAD_LDS16(Wb + (size_t)((k0) + w * 4 + q) * 2048, &Bt[buf][w * 4 + q][0]); }
#define AFL(k0, ks) (*(const short8*)(Ab + (size_t)((k0) + (ks) * 16 + hi * 8) * 32))

  floatx16 acc = {};
  short8 aA0 = AFL(0, 0), aA1 = AFL(0, 1);
  STAGE(0, 0);
  asm volatile("" ::: "memory");

  const int nt = N_EMBD >> 5;   // 32
  for (int t = 0; t < nt; ++t) {
    int k0 = t << 5, cur = t & 1;
    short8 aB0, aB1;
    if (t + 1 < nt) {
      aB0 = AFL(k0 + 32, 0); aB1 = AFL(k0 + 32, 1);
      STAGE(cur ^ 1, k0 + 32);
      __builtin_amdgcn_sched_barrier(0);
      asm volatile("s_waitcnt vmcnt(6)" ::: "memory");
    } else {
      __builtin_amdgcn_sched_barrier(0);
      asm volatile("s_waitcnt vmcnt(0)" ::: "memory");
    }
    __builtin_amdgcn_s_barrier();
    __builtin_amdgcn_sched_barrier(0);
    short8 bf0, bf1;
#pragma unroll
    for (int jj = 0; jj < 8; ++jj) bf0[jj] = (short)f2bf(Bt[cur][hi * 8 + jj][w * 32 + lo]);
#pragma unroll
    for (int jj = 0; jj < 8; ++jj) bf1[jj] = (short)f2bf(Bt[cur][16 + hi * 8 + jj][w * 32 + lo]);
    acc = __builtin_amdgcn_mfma_f32_32x32x16_bf16(aA0, bf0, acc, 0, 0, 0);
    acc = __builtin_amdgcn_mfma_f32_32x32x16_bf16(aA1, bf1, acc, 0, 0, 0);
    __builtin_amdgcn_sched_barrier(0);
    __builtin_amdgcn_s_barrier();
    __builtin_amdgcn_sched_barrier(0);
    aA0 = aB0; aA1 = aB1;
  }
#undef STAGE
#undef AFL

#pragma unroll
  for (int r = 0; r < 16; ++r) {
    int row = (r & 3) + 8 * (r >> 2) + 4 * hi;  // batch index
    out[(size_t)row * NW + off + c0 + w * 32 + lo] = acc[r];
  }
}

extern "C" void kernel_launch(void* const* d_in, const int* in_sizes, int n_in,
                              void* d_out, int out_size, void* d_ws, size_t ws_size,
                              hipStream_t stream) {
  const float* P  = (const float*)d_in[0];
  const float* We = (const float*)d_in[1];
  const float* Wd = (const float*)d_in[2];
  const float* g  = (const float*)d_in[3];
  const float* bt = (const float*)d_in[4];
  float* out = (float*)d_out;

  unsigned short* xswz   = (unsigned short*)d_ws;                    // NW*32 bf16 = 7.08 MB
  unsigned short* reps   = xswz + (size_t)NW * 32;                   // 6.29 MB
  unsigned short* rlnswz = reps + (size_t)NCHUNK * 32 * N_EMBD;      // 6.29 MB

  xpose_kernel<<<(NW / 8) * 32 / 256, 256, 0, stream>>>(P, xswz);
  enc_kernel<<<384, 512, 0, stream>>>(xswz, We, reps);
  ln_kernel<<<768, 256, 0, stream>>>(reps, g, bt, rlnswz);
  dec_kernel<<<432, 512, 0, stream>>>(rlnswz, Wd, out);
}